// Round 1
// 407.063 us; speedup vs baseline: 1.0041x; 1.0041x over previous
//
#include <hip/hip_runtime.h>

// DrawRope fused: one kernel zeroes each frame (coalesced int4 stores, L2-hot)
// and immediately rasterizes lines + endpoints into it. Replaces the previous
// memset(1.5GB-coverage) + separate draw kernel (two serialized dispatches,
// fill at 9.8% occupancy, draw hitting cold L2).

#define IMAGE_H 200
#define IMAGE_W 200
#define FRAME_INTS (IMAGE_H * IMAGE_W * 3)   // 120000 ints per frame (480 KB)
#define FRAME_INT4S (FRAME_INTS / 4)         // 30000 int4 stores per frame
#define NTHREADS 1024                        // 16 waves/block; 2 blocks/CU = 100% occ

__device__ __forceinline__ void draw_segment(int* img, int c0, int r0, int c1, int r1) {
    // Exact replica of the reference Bresenham (inclusive endpoints).
    int dx = abs(c1 - c0);
    int dy = -abs(r1 - r0);
    int sc = (c0 < c1) ? 1 : -1;
    int sr = (r0 < r1) ? 1 : -1;
    int err = dx + dy;
    int c = c0, r = r0;
    while (true) {
        int* p = img + (r * IMAGE_W + c) * 3;
        p[0] = 128; p[1] = 128; p[2] = 128;
        if (c == c1 && r == r1) break;
        int e2 = 2 * err;
        if (e2 >= dy) { err += dy; c += sc; }
        if (e2 <= dx) { err += dx; r += sr; }
    }
}

__global__ __launch_bounds__(NTHREADS)
void draw_rope_fused(const float* __restrict__ x,
                     const float* __restrict__ resolution,
                     const float* __restrict__ origin,
                     int* __restrict__ out) {
    const int m = blockIdx.x;  // frame index in [0, B*T)
    int* img = out + (size_t)m * FRAME_INTS;

    // ---- Phase 1: zero this frame with coalesced 16B stores ----
    // base byte offset m*480000 is 16B-aligned; consecutive lanes hit
    // consecutive int4s -> 1 KB per wave store instruction.
    int4* p4 = (int4*)img;
    const int4 z = make_int4(0, 0, 0, 0);
    for (int i = threadIdx.x; i < FRAME_INT4S; i += NTHREADS) p4[i] = z;

    // Pixel coords, exactly as reference (fp32): row = floor(y/res0+org0),
    // col = floor(x/res1+org1). Uniform across the block -> scalar loads/ALU.
    const float res0 = resolution[0], res1 = resolution[1];
    const float org0 = origin[0],    org1 = origin[1];
    const float* xp = x + (size_t)m * 6;
    int rows[3], cols[3];
#pragma unroll
    for (int i = 0; i < 3; ++i) {
        rows[i] = (int)floorf(xp[2 * i + 1] / res0 + org0);
        cols[i] = (int)floorf(xp[2 * i + 0] / res1 + org1);
    }

    __syncthreads();  // frame fully zeroed (vmcnt drained) before line stores

    // ---- Phase 2: lanes 0,1 draw segments p0->p1, p1->p2 (all writes 128,
    // overlap between segments benign). Lines are L2-hot from phase 1.
    if (threadIdx.x < 2) {
        const int s = threadIdx.x;
        draw_segment(img, cols[s], rows[s], cols[s + 1], rows[s + 1]);
    }
    __syncthreads();  // line stores drained before endpoint overwrites

    // ---- Phase 3: endpoints in reference scatter order (red p0, red p1, green p2).
    if (threadIdx.x == 0) {
        int* p0 = img + (rows[0] * IMAGE_W + cols[0]) * 3;
        p0[0] = 255; p0[1] = 0; p0[2] = 0;
        int* p1 = img + (rows[1] * IMAGE_W + cols[1]) * 3;
        p1[0] = 255; p1[1] = 0; p1[2] = 0;
        int* p2 = img + (rows[2] * IMAGE_W + cols[2]) * 3;
        p2[0] = 0; p2[1] = 255; p2[2] = 0;
    }
}

extern "C" void kernel_launch(void* const* d_in, const int* in_sizes, int n_in,
                              void* d_out, int out_size, void* d_ws, size_t ws_size,
                              hipStream_t stream) {
    const float* x          = (const float*)d_in[0];  // [B,T,6]
    const float* resolution = (const float*)d_in[1];  // [2]
    const float* origin     = (const float*)d_in[2];  // [2]
    int* out                = (int*)d_out;            // [B,T,200,200,3] int32

    const int M = in_sizes[0] / 6;  // B*T = 800 frames

    // Safety: previous kernel zeroed out_size*sizeof(int) bytes. If the harness
    // buffer extends past the M frames we write, zero that (disjoint) tail so
    // coverage is identical. No-op when out_size == M*FRAME_INTS.
    const size_t frame_total = (size_t)M * FRAME_INTS;
    if ((size_t)out_size > frame_total) {
        hipMemsetAsync((char*)d_out + frame_total * sizeof(int), 0,
                       ((size_t)out_size - frame_total) * sizeof(int), stream);
    }

    // One fused dispatch: zero + draw, per-frame, L2-hot.
    draw_rope_fused<<<M, NTHREADS, 0, stream>>>(x, resolution, origin, out);
}